// Round 4
// baseline (232.971 us; speedup 1.0000x reference)
//
#include <hip/hip_runtime.h>
#include <cstdint>
#include <cstddef>

typedef __attribute__((ext_vector_type(8))) short bf16x8;
typedef __attribute__((ext_vector_type(4))) short s16x4;
typedef __attribute__((ext_vector_type(2))) short s16x2;
typedef __attribute__((ext_vector_type(4))) float f32x4;
typedef __attribute__((ext_vector_type(16))) float f32x16;
typedef __attribute__((ext_vector_type(4))) unsigned u32x4;

#define DEVI static __device__ __forceinline__

DEVI short f2bf(float f){
  unsigned u = __builtin_bit_cast(unsigned, f);
  u += 0x7fffu + ((u >> 16) & 1u);
  return (short)(u >> 16);
}
DEVI float bf2f(short s){
  unsigned u = ((unsigned)(unsigned short)s) << 16;
  return __builtin_bit_cast(float, u);
}
// packed RNE f32->bf16 pair (low = a, high = b). v_cvt_pk_bf16_f32 is NOT
// round-to-nearest-even (R1 post-mortem: swapping it in tripled absmax);
// software RNE matches the reference-passing numerics exactly.
DEVI unsigned pack_bf16_rne(float a, float b){
  unsigned ua = __builtin_bit_cast(unsigned, a);
  unsigned ub = __builtin_bit_cast(unsigned, b);
  ua += 0x7fffu + ((ua >> 16) & 1u);
  ub += 0x7fffu + ((ub >> 16) & 1u);
  return (ua >> 16) | (ub & 0xffff0000u);
}
// async global->LDS DMA, 16B per lane. LDS dest is wave-uniform base + lane*16
// (linear); swizzled layouts are realized by pre-swizzling the per-lane GLOBAL
// source address (guide §5 caveat; m173 pattern).
DEVI void g2l16(const short* g, short* l){
  __builtin_amdgcn_global_load_lds((const __attribute__((address_space(1))) void*)g,
                                   (__attribute__((address_space(3))) void*)l, 16, 0, 0);
}

DEVI f32x4 mfma16(bf16x8 a, bf16x8 b, f32x4 c){
  return __builtin_amdgcn_mfma_f32_16x16x32_bf16(a, b, c, 0, 0, 0);
}
DEVI f32x16 mfma32(bf16x8 a, bf16x8 b, f32x16 c){
  return __builtin_amdgcn_mfma_f32_32x32x16_bf16(a, b, c, 0, 0, 0);
}

// q pre-scale: C^-0.5 * log2(e) so attention runs in exp2 domain
#define QSC 0.09016844005555897f
// fixed softmax "max" (exp2 domain): exact math (normalization cancels it);
// scores bounded ~N(0,1.44) so p=exp2(s-8) can neither overflow nor denormal.
#define FIXM 8.0f

// ---------------- kernel 1: fp32 weights -> bf16 ----------------
__global__ __launch_bounds__(256) void k_conv(const float* __restrict__ wq, const float* __restrict__ wp,
                                              short* __restrict__ wqb, short* __restrict__ wpb){
  int t = blockIdx.x * 256 + threadIdx.x;
  for (int i = t; i < 768 * 256; i += 256 * 256) wqb[i] = f2bf(wq[i]);
  if (t < 256 * 256) wpb[t] = f2bf(wp[t]);
}

// ---------------- kernel 2: groupnorm stats ----------------
__global__ __launch_bounds__(256) void k_stats(const float* __restrict__ x, float2* __restrict__ st){
  int b = blockIdx.x >> 5, g = blockIdx.x & 31;
  const f32x4* p = (const f32x4*)(x + ((size_t)(b * 256 + g * 8)) * 4096);
  float s = 0.f, ss = 0.f;
  for (int i = threadIdx.x; i < 8192; i += 256){
    f32x4 v = p[i];
    s  += v[0] + v[1] + v[2] + v[3];
    ss += v[0]*v[0] + v[1]*v[1] + v[2]*v[2] + v[3]*v[3];
  }
  for (int d = 32; d; d >>= 1){ s += __shfl_down(s, d); ss += __shfl_down(ss, d); }
  __shared__ float a0[4], a1[4];
  int w = threadIdx.x >> 6;
  if ((threadIdx.x & 63) == 0){ a0[w] = s; a1[w] = ss; }
  __syncthreads();
  if (threadIdx.x == 0){
    s = a0[0] + a0[1] + a0[2] + a0[3];
    ss = a1[0] + a1[1] + a1[2] + a1[3];
    float mean = s * (1.f / 32768.f);
    float var = ss * (1.f / 32768.f) - mean * mean;
    st[blockIdx.x] = make_float2(mean, rsqrtf(var + 1e-5f));
  }
}

// ---------------- kernel 3: normalize + transpose -> h_t (B,N,C) bf16 ----------------
__global__ __launch_bounds__(256) void k_norm(const float* __restrict__ x, const float2* __restrict__ st,
                                              const float* __restrict__ gw, const float* __restrict__ gb,
                                              short* __restrict__ h_t){
  __shared__ short t[256][66];
  int b = blockIdx.x >> 6;
  int n0 = (blockIdx.x & 63) * 64;
  int tid = threadIdx.x;
  for (int r = 0; r < 16; ++r){
    int idx = tid + r * 256;
    int c = idx >> 4, ch = idx & 15;
    f32x4 v = *(const f32x4*)(x + ((size_t)(b * 256 + c)) * 4096 + n0 + ch * 4);
    float2 s = st[b * 32 + (c >> 3)];
    float wv = gw[c] * s.y;
    float bv = gb[c] - s.x * wv;
    s16x2 p0, p1;
    p0[0] = f2bf(v[0] * wv + bv); p0[1] = f2bf(v[1] * wv + bv);
    p1[0] = f2bf(v[2] * wv + bv); p1[1] = f2bf(v[3] * wv + bv);
    *(s16x2*)&t[c][ch * 4]     = p0;
    *(s16x2*)&t[c][ch * 4 + 2] = p1;
  }
  __syncthreads();
  for (int r = 0; r < 8; ++r){
    int idx = tid + r * 256;
    int n = idx >> 5, cc = idx & 31;
    bf16x8 pk;
    #pragma unroll
    for (int j = 0; j < 8; ++j) pk[j] = t[cc * 8 + j][n];
    *(bf16x8*)(h_t + ((size_t)(b * 4096 + n0 + n)) * 256 + cc * 8) = pk;
  }
}

// ---------------- kernel 4/6: 128x128-tile bf16 MFMA GEMM ----------------
__global__ __launch_bounds__(256) void k_gemm(const short* __restrict__ A,
                                              const short* __restrict__ Bsrc,
                                              const float* __restrict__ bias,
                                              int mtiles, int mode,
                                              short* __restrict__ q_t, short* __restrict__ k_t,
                                              short* __restrict__ v_,
                                              const float* __restrict__ xres, float* __restrict__ outp)
{
  __shared__ short a_s[128 * 72];
  __shared__ short b_s[128 * 72];
  int t = blockIdx.x;
  int mt = t % mtiles; t /= mtiles;
  int nt = t & 31; int b = t >> 5;
  int o0 = mt * 128, n0 = nt * 128;
  int tid = threadIdx.x;
  int lane = tid & 63, w = tid >> 6;
  int col = lane & 15, quad = lane >> 4;
  int wo = (w >> 1) * 64, wn = (w & 1) * 64;

  f32x4 acc[4][4];
  #pragma unroll
  for (int i = 0; i < 4; ++i)
    #pragma unroll
    for (int j = 0; j < 4; ++j)
      #pragma unroll
      for (int r = 0; r < 4; ++r) acc[i][j][r] = 0.f;

  for (int kk = 0; kk < 4; ++kk){
    int k0 = kk * 64;
    #pragma unroll
    for (int r = 0; r < 4; ++r){
      int idx = tid + r * 256;
      int row = idx >> 3, ch = idx & 7;
      *(bf16x8*)&a_s[row * 72 + ch * 8] = *(const bf16x8*)(A + (size_t)(o0 + row) * 256 + k0 + ch * 8);
      *(bf16x8*)&b_s[row * 72 + ch * 8] = *(const bf16x8*)(Bsrc + ((size_t)(b * 4096 + n0 + row)) * 256 + k0 + ch * 8);
    }
    __syncthreads();
    #pragma unroll
    for (int kc = 0; kc < 2; ++kc){
      bf16x8 af[4], bfr[4];
      #pragma unroll
      for (int i = 0; i < 4; ++i) af[i]  = *(bf16x8*)&a_s[(wo + i * 16 + col) * 72 + kc * 32 + quad * 8];
      #pragma unroll
      for (int j = 0; j < 4; ++j) bfr[j] = *(bf16x8*)&b_s[(wn + j * 16 + col) * 72 + kc * 32 + quad * 8];
      #pragma unroll
      for (int i = 0; i < 4; ++i)
        #pragma unroll
        for (int j = 0; j < 4; ++j)
          acc[i][j] = mfma16(af[i], bfr[j], acc[i][j]);
    }
    __syncthreads();
  }

  float bv[4][4];
  #pragma unroll
  for (int i = 0; i < 4; ++i)
    #pragma unroll
    for (int r = 0; r < 4; ++r) bv[i][r] = bias[o0 + wo + i * 16 + quad * 4 + r];

  if (mode == 0){
    int region = o0 >> 8;              // 0=q 1=k 2=v (block-uniform)
    int obase = (o0 & 255) + wo;
    if (region < 2){
      short* dst = region ? k_t : q_t;
      float sc = region ? 1.0f : QSC;
      #pragma unroll
      for (int i = 0; i < 4; ++i)
        #pragma unroll
        for (int j = 0; j < 4; ++j){
          int n = n0 + wn + j * 16 + col;
          s16x4 pk;
          #pragma unroll
          for (int r = 0; r < 4; ++r) pk[r] = f2bf((acc[i][j][r] + bv[i][r]) * sc);
          *(s16x4*)(dst + ((size_t)(b * 4096 + n)) * 256 + obase + i * 16 + quad * 4) = pk;
        }
    } else {
      #pragma unroll
      for (int i = 0; i < 4; ++i)
        #pragma unroll
        for (int r = 0; r < 4; ++r){
          int oo = obase + i * 16 + quad * 4 + r;
          #pragma unroll
          for (int j = 0; j < 4; ++j){
            int n = n0 + wn + j * 16 + col;
            v_[((size_t)(b * 256 + oo)) * 4096 + n] = f2bf(acc[i][j][r] + bv[i][r]);
          }
        }
    }
  } else {
    #pragma unroll
    for (int i = 0; i < 4; ++i)
      #pragma unroll
      for (int r = 0; r < 4; ++r){
        int oo = o0 + wo + i * 16 + quad * 4 + r;
        #pragma unroll
        for (int j = 0; j < 4; ++j){
          int n = n0 + wn + j * 16 + col;
          size_t off = ((size_t)(b * 256 + oo)) * 4096 + n;
          outp[off] = xres[off] + acc[i][j][r] + bv[i][r];
        }
      }
  }
}

// ---------------- kernel 5: flash attention (fixed-max softmax, in-reg P, DMA dbuf) ----------------
// grid = 512: (chunk=idx&15, qt=idx>>4); block = 4 waves x 32 q-rows = 128 q; BM=32.
// Staging: global_load_lds DOUBLE-buffer (zero staging registers -- R2's dbuf
// failure was the +32 live VGPRs of reg-staged dbuf, not dbuf itself). DMA for
// tile it+1 is issued at the top of iter it into the other buffer and flies
// under the whole compute phase; the end-of-iter __syncthreads (vmcnt drain +
// barrier) is the only sync. XOR bank swizzles are applied on the per-lane
// GLOBAL source address (LDS dest must be linear: wave-uniform base + lane*16).
// QK^T computed transposed (S^T = mfma32(K, Q)) so each lane owns P for q = lane&31:
// softmax + RNE bf16 pack + h-half exchange (shfl_xor 32) fully in registers.
// S accumulated in two independent 8-deep MFMA chains (sa/sb) to break the
// 16-deep dependent-accumulate chain.
__global__ __launch_bounds__(256, 2) void k_attn(const short* __restrict__ q_t, const short* __restrict__ k_t,
                                                 const short* __restrict__ v_,
                                                 short* __restrict__ o_part, float* __restrict__ lsum)
{
  __shared__ short k_s[2][32 * 256];   // [m][c], 16B chunk pos c holds source chunk c^(m&7)
  __shared__ short v_s[2][256 * 32];   // [c][m], 16B chunk pos p holds source chunk p^((c>>1)&3)
  int idx = blockIdx.x;
  int qt = idx >> 4;
  int chunk = idx & 15;
  int b  = chunk >> 2;
  int ck = chunk & 3;
  int q0 = qt * 128;
  int tid = threadIdx.x, lane = tid & 63, w = tid >> 6;
  int col = lane & 31, h = lane >> 5;

  // Q fragments: 32 q/wave, full K=256 resident (16 frags = 64 VGPR).
  const short* qp = q_t + ((size_t)(b * 4096 + q0 + w * 32 + col)) * 256 + h * 8;
  bf16x8 qf[16];
  #pragma unroll
  for (int ks2 = 0; ks2 < 16; ++ks2) qf[ks2] = *(const bf16x8*)(qp + ks2 * 16);

  const short* kcb = k_t + ((size_t)(b * 4096 + ck * 1024)) * 256;
  const short* vcb = v_  + ((size_t)b) * 256 * 4096 + ck * 1024;

  // per-lane pre-swizzled global source offsets (shorts) for the DMA staging.
  // K: wave w, instr i writes LDS rows 8w+2i..+1 linearly; lane l -> row
  // r = 8w+2i+(l>>5), stored pos c = l&31, content = source chunk c^(r&7).
  // V: wave w, instr i writes LDS rows 64w+16i..+15; lane l -> row
  // rv = 64w+16i+(l>>2), stored pos p = l&3, content = source chunk p^((rv>>1)&3).
  int koff[4], voff[4];
  #pragma unroll
  for (int i = 0; i < 4; ++i){
    int r  = w * 8 + 2 * i + (lane >> 5);
    koff[i] = r * 256 + (((lane & 31) ^ (r & 7)) * 8);
    int rv = w * 64 + 16 * i + (lane >> 2);
    voff[i] = rv * 4096 + (((lane & 3) ^ ((rv >> 1) & 3)) * 8);
  }

  auto STAGE = [&](int bufi, int itt){
    const short* kg = kcb + itt * 8192;   // +32 rows * 256
    const short* vg = vcb + itt * 32;     // +32 m-columns
    short* kl = (short*)k_s[bufi];
    short* vl = (short*)v_s[bufi];
    #pragma unroll
    for (int i = 0; i < 4; ++i)
      g2l16(kg + koff[i], kl + (w * 8 + 2 * i) * 256);
    #pragma unroll
    for (int i = 0; i < 4; ++i)
      g2l16(vg + voff[i], vl + (w * 64 + 16 * i) * 32);
  };

  f32x16 o_acc[8];
  #pragma unroll
  for (int ct = 0; ct < 8; ++ct)
    #pragma unroll
    for (int r = 0; r < 16; ++r) o_acc[ct][r] = 0.f;
  float l_acc = 0.f;

  STAGE(0, 0);
  __syncthreads();

  #pragma unroll 1
  for (int it = 0; it < 32; ++it){
    int cur = it & 1;
    if (it < 31) STAGE(cur ^ 1, it + 1);   // DMA flies under this iter's compute
    const short* kc = k_s[cur];
    const short* vc = v_s[cur];

    // ---- S^T = K Q^T : 16 mfma(32x32x16) in 2 independent chains ----
    f32x16 sa, sb;
    #pragma unroll
    for (int r = 0; r < 16; ++r){ sa[r] = 0.f; sb[r] = 0.f; }
    #pragma unroll
    for (int j = 0; j < 8; ++j){
      bf16x8 kb0 = *(const bf16x8*)&kc[col * 256 + ((((4 * j)     + h) ^ (col & 7)) * 8)];
      bf16x8 kb1 = *(const bf16x8*)&kc[col * 256 + ((((4 * j + 2) + h) ^ (col & 7)) * 8)];
      sa = mfma32(kb0, qf[2 * j],     sa);
      sb = mfma32(kb1, qf[2 * j + 1], sb);
    }
    #pragma unroll
    for (int r = 0; r < 16; ++r) sa[r] += sb[r];

    // ---- fixed-max softmax, fully in registers, two halves ----
    // lane holds p[q = lane&31][m = (r&3) + 8*(r>>2) + 4*h]
    bf16x8 pa0, pa1;
    {
      float p0 = __builtin_amdgcn_exp2f(sa[0] - FIXM);
      float p1 = __builtin_amdgcn_exp2f(sa[1] - FIXM);
      float p2 = __builtin_amdgcn_exp2f(sa[2] - FIXM);
      float p3 = __builtin_amdgcn_exp2f(sa[3] - FIXM);
      float p4 = __builtin_amdgcn_exp2f(sa[4] - FIXM);
      float p5 = __builtin_amdgcn_exp2f(sa[5] - FIXM);
      float p6 = __builtin_amdgcn_exp2f(sa[6] - FIXM);
      float p7 = __builtin_amdgcn_exp2f(sa[7] - FIXM);
      l_acc += p0 + p1 + p2 + p3 + p4 + p5 + p6 + p7;
      unsigned A0 = pack_bf16_rne(p0, p1), A1 = pack_bf16_rne(p2, p3);
      unsigned B0 = pack_bf16_rne(p4, p5), B1 = pack_bf16_rne(p6, p7);
      unsigned sA0 = __shfl_xor(A0, 32), sA1 = __shfl_xor(A1, 32);
      unsigned sB0 = __shfl_xor(B0, 32), sB1 = __shfl_xor(B1, 32);
      u32x4 w0;
      w0[0] = h ? sB0 : A0;  w0[1] = h ? sB1 : A1;
      w0[2] = h ? B0 : sA0;  w0[3] = h ? B1 : sA1;
      pa0 = __builtin_bit_cast(bf16x8, w0);   // m 0..15
    }
    {
      float p0 = __builtin_amdgcn_exp2f(sa[8]  - FIXM);
      float p1 = __builtin_amdgcn_exp2f(sa[9]  - FIXM);
      float p2 = __builtin_amdgcn_exp2f(sa[10] - FIXM);
      float p3 = __builtin_amdgcn_exp2f(sa[11] - FIXM);
      float p4 = __builtin_amdgcn_exp2f(sa[12] - FIXM);
      float p5 = __builtin_amdgcn_exp2f(sa[13] - FIXM);
      float p6 = __builtin_amdgcn_exp2f(sa[14] - FIXM);
      float p7 = __builtin_amdgcn_exp2f(sa[15] - FIXM);
      l_acc += p0 + p1 + p2 + p3 + p4 + p5 + p6 + p7;
      unsigned C0 = pack_bf16_rne(p0, p1), C1 = pack_bf16_rne(p2, p3);
      unsigned D0 = pack_bf16_rne(p4, p5), D1 = pack_bf16_rne(p6, p7);
      unsigned sC0 = __shfl_xor(C0, 32), sC1 = __shfl_xor(C1, 32);
      unsigned sD0 = __shfl_xor(D0, 32), sD1 = __shfl_xor(D1, 32);
      u32x4 w1;
      w1[0] = h ? sD0 : C0;  w1[1] = h ? sD1 : C1;
      w1[2] = h ? D0 : sC0;  w1[3] = h ? D1 : sC1;
      pa1 = __builtin_bit_cast(bf16x8, w1);   // m 16..31
    }

    // ---- O += P V : 16 mfma(32x32x16), A-frags from registers ----
    #pragma unroll
    for (int ct = 0; ct < 8; ++ct){
      int c = ct * 32 + col;
      int sw = (c >> 1) & 3;
      bf16x8 vf0 = *(const bf16x8*)&vc[c * 32 + ((h ^ sw) * 8)];
      bf16x8 vf1 = *(const bf16x8*)&vc[c * 32 + (((2 + h) ^ sw) * 8)];
      o_acc[ct] = mfma32(pa0, vf0, o_acc[ct]);
      o_acc[ct] = mfma32(pa1, vf1, o_acc[ct]);
    }

    // end-of-iter: drain DMA (vmcnt) + barrier -> next buffer valid, this
    // buffer free for the DMA issued in it+1.
    if (it < 31) __syncthreads();
  }

  // ---- epilogue: un-normalized partial (bf16) + per-row l ----
  short* op = o_part + (((size_t)(ck * 4 + b)) * 4096 + q0 + w * 32) * 256;
  #pragma unroll
  for (int r = 0; r < 16; ++r){
    int q = (r & 3) + 8 * (r >> 2) + 4 * h;
    #pragma unroll
    for (int ct = 0; ct < 8; ++ct)
      op[(size_t)q * 256 + ct * 32 + col] = f2bf(o_acc[ct][r]);
  }
  l_acc += __shfl_xor(l_acc, 32);
  if (h == 0)
    lsum[((size_t)(ck * 4 + b)) * 4096 + q0 + w * 32 + col] = l_acc;
}

// ---------------- kernel 5b: combine KV-split partials -> o_t (B,N,C) bf16 ----------------
// shared fixed M across chunks: out = (sum O_ck) / (sum l_ck)
__global__ __launch_bounds__(256) void k_comb(const short* __restrict__ o_part, const float* __restrict__ lsum,
                                              short* __restrict__ o_t)
{
  int t = blockIdx.x * 256 + threadIdx.x;
  int row = t >> 5;                          // b*4096 + n
  int c8 = (t & 31) * 8;
  float inv = 1.f / (lsum[row] + lsum[16384 + row] + lsum[2 * 16384 + row] + lsum[3 * 16384 + row]);
  size_t base = (size_t)row * 256 + c8;
  const size_t CS = (size_t)16384 * 256;
  bf16x8 a0 = *(const bf16x8*)(o_part + base);
  bf16x8 a1 = *(const bf16x8*)(o_part + CS + base);
  bf16x8 a2 = *(const bf16x8*)(o_part + 2 * CS + base);
  bf16x8 a3 = *(const bf16x8*)(o_part + 3 * CS + base);
  bf16x8 outv;
  #pragma unroll
  for (int j = 0; j < 8; ++j)
    outv[j] = f2bf((bf2f(a0[j]) + bf2f(a1[j]) + bf2f(a2[j]) + bf2f(a3[j])) * inv);
  *(bf16x8*)(o_t + base) = outv;
}

extern "C" void kernel_launch(void* const* d_in, const int* in_sizes, int n_in,
                              void* d_out, int out_size, void* d_ws, size_t ws_size,
                              hipStream_t stream)
{
  const float* x     = (const float*)d_in[0];
  const float* gw    = (const float*)d_in[1];
  const float* gb    = (const float*)d_in[2];
  const float* qkvw  = (const float*)d_in[3];
  const float* qkvb  = (const float*)d_in[4];
  const float* projw = (const float*)d_in[5];
  const float* projb = (const float*)d_in[6];
  float* out = (float*)d_out;

  char* ws = (char*)d_ws;
  float2* stats = (float2*)ws;                         // 1 KB
  short* wqb = (short*)(ws + 1024);                    // 384 KB
  short* wpb = (short*)(ws + 1024 + 393216);           // 128 KB
  short* h_t = (short*)(ws + 1024 + 393216 + 131072);  // 8 MB buffers follow
  const size_t BIG = (size_t)4 * 4096 * 256;           // elements (8 MB as bf16)
  short* q_t = h_t + BIG;
  short* k_t = q_t + BIG;
  short* v_  = k_t + BIG;
  short* o_t = v_  + BIG;
  short* o_part = o_t + BIG;                           // 4 chunks x 8 MB = 32 MB
  float* lsum = (float*)(o_part + 4 * BIG);            // 256 KB

  k_conv <<<dim3(256),  dim3(256), 0, stream>>>(qkvw, projw, wqb, wpb);
  k_stats<<<dim3(128),  dim3(256), 0, stream>>>(x, stats);
  k_norm <<<dim3(256),  dim3(256), 0, stream>>>(x, stats, gw, gb, h_t);
  k_gemm <<<dim3(768),  dim3(256), 0, stream>>>(wqb, h_t, qkvb, 6, 0, q_t, k_t, v_,
                                                (const float*)nullptr, (float*)nullptr);
  k_attn <<<dim3(512),  dim3(256), 0, stream>>>(q_t, k_t, v_, o_part, lsum);
  k_comb <<<dim3(2048), dim3(256), 0, stream>>>(o_part, lsum, o_t);
  k_gemm <<<dim3(256),  dim3(256), 0, stream>>>(wpb, o_t, projb, 2, 1,
                                                (short*)nullptr, (short*)nullptr, (short*)nullptr,
                                                x, out);
}

// Round 5
// 225.644 us; speedup vs baseline: 1.0325x; 1.0325x over previous
//
#include <hip/hip_runtime.h>
#include <cstdint>
#include <cstddef>

typedef __attribute__((ext_vector_type(8))) short bf16x8;
typedef __attribute__((ext_vector_type(4))) short s16x4;
typedef __attribute__((ext_vector_type(2))) short s16x2;
typedef __attribute__((ext_vector_type(4))) float f32x4;
typedef __attribute__((ext_vector_type(16))) float f32x16;
typedef __attribute__((ext_vector_type(4))) unsigned u32x4;

#define DEVI static __device__ __forceinline__

DEVI short f2bf(float f){
  unsigned u = __builtin_bit_cast(unsigned, f);
  u += 0x7fffu + ((u >> 16) & 1u);
  return (short)(u >> 16);
}
DEVI float bf2f(short s){
  unsigned u = ((unsigned)(unsigned short)s) << 16;
  return __builtin_bit_cast(float, u);
}
// packed RNE f32->bf16 pair (low = a, high = b). v_cvt_pk_bf16_f32 is NOT
// round-to-nearest-even (R1 post-mortem: swapping it in tripled absmax);
// software RNE matches the reference-passing numerics exactly.
DEVI unsigned pack_bf16_rne(float a, float b){
  unsigned ua = __builtin_bit_cast(unsigned, a);
  unsigned ub = __builtin_bit_cast(unsigned, b);
  ua += 0x7fffu + ((ua >> 16) & 1u);
  ub += 0x7fffu + ((ub >> 16) & 1u);
  return (ua >> 16) | (ub & 0xffff0000u);
}
// async global->LDS DMA, 16B per lane. LDS dest is wave-uniform base + lane*16
// (linear); swizzled layouts are realized by pre-swizzling the per-lane GLOBAL
// source address (guide §5 caveat; m173 pattern).
DEVI void g2l16(const short* g, short* l){
  __builtin_amdgcn_global_load_lds((const __attribute__((address_space(1))) void*)g,
                                   (__attribute__((address_space(3))) void*)l, 16, 0, 0);
}

DEVI f32x4 mfma16(bf16x8 a, bf16x8 b, f32x4 c){
  return __builtin_amdgcn_mfma_f32_16x16x32_bf16(a, b, c, 0, 0, 0);
}
DEVI f32x16 mfma32(bf16x8 a, bf16x8 b, f32x16 c){
  return __builtin_amdgcn_mfma_f32_32x32x16_bf16(a, b, c, 0, 0, 0);
}

// q pre-scale: C^-0.5 * log2(e) so attention runs in exp2 domain
#define QSC 0.09016844005555897f
// fixed softmax "max" (exp2 domain): exact math (normalization cancels it);
// scores bounded ~N(0,1.44) so p=exp2(s-8) can neither overflow nor denormal.
#define FIXM 8.0f

// ---------------- kernel 1: fp32 weights -> bf16 ----------------
__global__ __launch_bounds__(256) void k_conv(const float* __restrict__ wq, const float* __restrict__ wp,
                                              short* __restrict__ wqb, short* __restrict__ wpb){
  int t = blockIdx.x * 256 + threadIdx.x;
  for (int i = t; i < 768 * 256; i += 256 * 256) wqb[i] = f2bf(wq[i]);
  if (t < 256 * 256) wpb[t] = f2bf(wp[t]);
}

// ---------------- kernel 2: groupnorm stats ----------------
__global__ __launch_bounds__(256) void k_stats(const float* __restrict__ x, float2* __restrict__ st){
  int b = blockIdx.x >> 5, g = blockIdx.x & 31;
  const f32x4* p = (const f32x4*)(x + ((size_t)(b * 256 + g * 8)) * 4096);
  float s = 0.f, ss = 0.f;
  for (int i = threadIdx.x; i < 8192; i += 256){
    f32x4 v = p[i];
    s  += v[0] + v[1] + v[2] + v[3];
    ss += v[0]*v[0] + v[1]*v[1] + v[2]*v[2] + v[3]*v[3];
  }
  for (int d = 32; d; d >>= 1){ s += __shfl_down(s, d); ss += __shfl_down(ss, d); }
  __shared__ float a0[4], a1[4];
  int w = threadIdx.x >> 6;
  if ((threadIdx.x & 63) == 0){ a0[w] = s; a1[w] = ss; }
  __syncthreads();
  if (threadIdx.x == 0){
    s = a0[0] + a0[1] + a0[2] + a0[3];
    ss = a1[0] + a1[1] + a1[2] + a1[3];
    float mean = s * (1.f / 32768.f);
    float var = ss * (1.f / 32768.f) - mean * mean;
    st[blockIdx.x] = make_float2(mean, rsqrtf(var + 1e-5f));
  }
}

// ---------------- kernel 3: normalize + transpose -> h_t (B,N,C) bf16 ----------------
__global__ __launch_bounds__(256) void k_norm(const float* __restrict__ x, const float2* __restrict__ st,
                                              const float* __restrict__ gw, const float* __restrict__ gb,
                                              short* __restrict__ h_t){
  __shared__ short t[256][66];
  int b = blockIdx.x >> 6;
  int n0 = (blockIdx.x & 63) * 64;
  int tid = threadIdx.x;
  for (int r = 0; r < 16; ++r){
    int idx = tid + r * 256;
    int c = idx >> 4, ch = idx & 15;
    f32x4 v = *(const f32x4*)(x + ((size_t)(b * 256 + c)) * 4096 + n0 + ch * 4);
    float2 s = st[b * 32 + (c >> 3)];
    float wv = gw[c] * s.y;
    float bv = gb[c] - s.x * wv;
    s16x2 p0, p1;
    p0[0] = f2bf(v[0] * wv + bv); p0[1] = f2bf(v[1] * wv + bv);
    p1[0] = f2bf(v[2] * wv + bv); p1[1] = f2bf(v[3] * wv + bv);
    *(s16x2*)&t[c][ch * 4]     = p0;
    *(s16x2*)&t[c][ch * 4 + 2] = p1;
  }
  __syncthreads();
  for (int r = 0; r < 8; ++r){
    int idx = tid + r * 256;
    int n = idx >> 5, cc = idx & 31;
    bf16x8 pk;
    #pragma unroll
    for (int j = 0; j < 8; ++j) pk[j] = t[cc * 8 + j][n];
    *(bf16x8*)(h_t + ((size_t)(b * 4096 + n0 + n)) * 256 + cc * 8) = pk;
  }
}

// ---------------- kernel 4/6: 128x128-tile bf16 MFMA GEMM ----------------
__global__ __launch_bounds__(256) void k_gemm(const short* __restrict__ A,
                                              const short* __restrict__ Bsrc,
                                              const float* __restrict__ bias,
                                              int mtiles, int mode,
                                              short* __restrict__ q_t, short* __restrict__ k_t,
                                              short* __restrict__ v_,
                                              const float* __restrict__ xres, float* __restrict__ outp)
{
  __shared__ short a_s[128 * 72];
  __shared__ short b_s[128 * 72];
  int t = blockIdx.x;
  int mt = t % mtiles; t /= mtiles;
  int nt = t & 31; int b = t >> 5;
  int o0 = mt * 128, n0 = nt * 128;
  int tid = threadIdx.x;
  int lane = tid & 63, w = tid >> 6;
  int col = lane & 15, quad = lane >> 4;
  int wo = (w >> 1) * 64, wn = (w & 1) * 64;

  f32x4 acc[4][4];
  #pragma unroll
  for (int i = 0; i < 4; ++i)
    #pragma unroll
    for (int j = 0; j < 4; ++j)
      #pragma unroll
      for (int r = 0; r < 4; ++r) acc[i][j][r] = 0.f;

  for (int kk = 0; kk < 4; ++kk){
    int k0 = kk * 64;
    #pragma unroll
    for (int r = 0; r < 4; ++r){
      int idx = tid + r * 256;
      int row = idx >> 3, ch = idx & 7;
      *(bf16x8*)&a_s[row * 72 + ch * 8] = *(const bf16x8*)(A + (size_t)(o0 + row) * 256 + k0 + ch * 8);
      *(bf16x8*)&b_s[row * 72 + ch * 8] = *(const bf16x8*)(Bsrc + ((size_t)(b * 4096 + n0 + row)) * 256 + k0 + ch * 8);
    }
    __syncthreads();
    #pragma unroll
    for (int kc = 0; kc < 2; ++kc){
      bf16x8 af[4], bfr[4];
      #pragma unroll
      for (int i = 0; i < 4; ++i) af[i]  = *(bf16x8*)&a_s[(wo + i * 16 + col) * 72 + kc * 32 + quad * 8];
      #pragma unroll
      for (int j = 0; j < 4; ++j) bfr[j] = *(bf16x8*)&b_s[(wn + j * 16 + col) * 72 + kc * 32 + quad * 8];
      #pragma unroll
      for (int i = 0; i < 4; ++i)
        #pragma unroll
        for (int j = 0; j < 4; ++j)
          acc[i][j] = mfma16(af[i], bfr[j], acc[i][j]);
    }
    __syncthreads();
  }

  float bv[4][4];
  #pragma unroll
  for (int i = 0; i < 4; ++i)
    #pragma unroll
    for (int r = 0; r < 4; ++r) bv[i][r] = bias[o0 + wo + i * 16 + quad * 4 + r];

  if (mode == 0){
    int region = o0 >> 8;              // 0=q 1=k 2=v (block-uniform)
    int obase = (o0 & 255) + wo;
    if (region < 2){
      short* dst = region ? k_t : q_t;
      float sc = region ? 1.0f : QSC;
      #pragma unroll
      for (int i = 0; i < 4; ++i)
        #pragma unroll
        for (int j = 0; j < 4; ++j){
          int n = n0 + wn + j * 16 + col;
          s16x4 pk;
          #pragma unroll
          for (int r = 0; r < 4; ++r) pk[r] = f2bf((acc[i][j][r] + bv[i][r]) * sc);
          *(s16x4*)(dst + ((size_t)(b * 4096 + n)) * 256 + obase + i * 16 + quad * 4) = pk;
        }
    } else {
      #pragma unroll
      for (int i = 0; i < 4; ++i)
        #pragma unroll
        for (int r = 0; r < 4; ++r){
          int oo = obase + i * 16 + quad * 4 + r;
          #pragma unroll
          for (int j = 0; j < 4; ++j){
            int n = n0 + wn + j * 16 + col;
            v_[((size_t)(b * 256 + oo)) * 4096 + n] = f2bf(acc[i][j][r] + bv[i][r]);
          }
        }
    }
  } else {
    #pragma unroll
    for (int i = 0; i < 4; ++i)
      #pragma unroll
      for (int r = 0; r < 4; ++r){
        int oo = o0 + wo + i * 16 + quad * 4 + r;
        #pragma unroll
        for (int j = 0; j < 4; ++j){
          int n = n0 + wn + j * 16 + col;
          size_t off = ((size_t)(b * 256 + oo)) * 4096 + n;
          outp[off] = xres[off] + acc[i][j][r] + bv[i][r];
        }
      }
  }
}

// ---------------- kernel 5: flash attention (fixed-max softmax, in-reg P, DMA dbuf) ----------------
// grid = 512: (chunk=idx&15, qt=idx>>4); block = 4 waves x 32 q-rows = 128 q; BM=32.
// Staging: global_load_lds DOUBLE-buffer, zero staging registers. DMA for tile
// it+1 issues at the top of iter it into the other buffer and flies under the
// whole compute phase; end-of-iter __syncthreads (vmcnt drain + barrier) is the
// only sync. XOR bank swizzles applied on the per-lane GLOBAL source address
// (LDS dest must be linear). QK^T single 16-deep accumulate chain (R4
// post-mortem: the sa/sb chain-split's +16 persistent VGPRs re-spilled --
// this kernel lives exactly at the 256-reg cliff; +16 regs = -25 us).
// QK^T computed transposed (S^T = mfma32(K, Q)) so each lane owns P for
// q = lane&31: softmax + RNE bf16 pack + h-half exchange fully in registers.
__global__ __launch_bounds__(256, 2) void k_attn(const short* __restrict__ q_t, const short* __restrict__ k_t,
                                                 const short* __restrict__ v_,
                                                 short* __restrict__ o_part, float* __restrict__ lsum)
{
  __shared__ short k_s[2][32 * 256];   // [m][c], 16B chunk pos c holds source chunk c^(m&7)
  __shared__ short v_s[2][256 * 32];   // [c][m], 16B chunk pos p holds source chunk p^((c>>1)&3)
  int idx = blockIdx.x;
  int qt = idx >> 4;
  int chunk = idx & 15;
  int b  = chunk >> 2;
  int ck = chunk & 3;
  int q0 = qt * 128;
  int tid = threadIdx.x, lane = tid & 63, w = tid >> 6;
  int col = lane & 31, h = lane >> 5;

  // Q fragments: 32 q/wave, full K=256 resident (16 frags = 64 VGPR).
  const short* qp = q_t + ((size_t)(b * 4096 + q0 + w * 32 + col)) * 256 + h * 8;
  bf16x8 qf[16];
  #pragma unroll
  for (int ks2 = 0; ks2 < 16; ++ks2) qf[ks2] = *(const bf16x8*)(qp + ks2 * 16);

  const short* kcb = k_t + ((size_t)(b * 4096 + ck * 1024)) * 256;
  const short* vcb = v_  + ((size_t)b) * 256 * 4096 + ck * 1024;

  // per-lane pre-swizzled global source offsets (shorts) for the DMA staging.
  // K: wave w, instr i writes LDS rows 8w+2i..+1 linearly; lane l -> row
  // r = 8w+2i+(l>>5), stored pos c = l&31, content = source chunk c^(r&7).
  // V: wave w, instr i writes LDS rows 64w+16i..+15; lane l -> row
  // rv = 64w+16i+(l>>2), stored pos p = l&3, content = source chunk p^((rv>>1)&3).
  int koff[4], voff[4];
  #pragma unroll
  for (int i = 0; i < 4; ++i){
    int r  = w * 8 + 2 * i + (lane >> 5);
    koff[i] = r * 256 + (((lane & 31) ^ (r & 7)) * 8);
    int rv = w * 64 + 16 * i + (lane >> 2);
    voff[i] = rv * 4096 + (((lane & 3) ^ ((rv >> 1) & 3)) * 8);
  }

  auto STAGE = [&](int bufi, int itt){
    const short* kg = kcb + itt * 8192;   // +32 rows * 256
    const short* vg = vcb + itt * 32;     // +32 m-columns
    short* kl = (short*)k_s[bufi];
    short* vl = (short*)v_s[bufi];
    #pragma unroll
    for (int i = 0; i < 4; ++i)
      g2l16(kg + koff[i], kl + (w * 8 + 2 * i) * 256);
    #pragma unroll
    for (int i = 0; i < 4; ++i)
      g2l16(vg + voff[i], vl + (w * 64 + 16 * i) * 32);
  };

  f32x16 o_acc[8];
  #pragma unroll
  for (int ct = 0; ct < 8; ++ct)
    #pragma unroll
    for (int r = 0; r < 16; ++r) o_acc[ct][r] = 0.f;
  float l_acc = 0.f;

  STAGE(0, 0);
  __syncthreads();

  #pragma unroll 1
  for (int it = 0; it < 32; ++it){
    int cur = it & 1;
    if (it < 31) STAGE(cur ^ 1, it + 1);   // DMA flies under this iter's compute
    const short* kc = k_s[cur];
    const short* vc = v_s[cur];

    // ---- S^T = K Q^T : 16 mfma(32x32x16), single chain (register-neutral) ----
    f32x16 s;
    #pragma unroll
    for (int r = 0; r < 16; ++r) s[r] = 0.f;
    #pragma unroll
    for (int ks2 = 0; ks2 < 16; ++ks2){
      bf16x8 kb = *(const bf16x8*)&kc[col * 256 + (((ks2 * 2 + h) ^ (col & 7)) * 8)];
      s = mfma32(kb, qf[ks2], s);
    }

    // ---- fixed-max softmax, fully in registers, two halves ----
    // lane holds p[q = lane&31][m = (r&3) + 8*(r>>2) + 4*h]
    bf16x8 pa0, pa1;
    {
      float p0 = __builtin_amdgcn_exp2f(s[0] - FIXM);
      float p1 = __builtin_amdgcn_exp2f(s[1] - FIXM);
      float p2 = __builtin_amdgcn_exp2f(s[2] - FIXM);
      float p3 = __builtin_amdgcn_exp2f(s[3] - FIXM);
      float p4 = __builtin_amdgcn_exp2f(s[4] - FIXM);
      float p5 = __builtin_amdgcn_exp2f(s[5] - FIXM);
      float p6 = __builtin_amdgcn_exp2f(s[6] - FIXM);
      float p7 = __builtin_amdgcn_exp2f(s[7] - FIXM);
      l_acc += p0 + p1 + p2 + p3 + p4 + p5 + p6 + p7;
      unsigned A0 = pack_bf16_rne(p0, p1), A1 = pack_bf16_rne(p2, p3);
      unsigned B0 = pack_bf16_rne(p4, p5), B1 = pack_bf16_rne(p6, p7);
      unsigned sA0 = __shfl_xor(A0, 32), sA1 = __shfl_xor(A1, 32);
      unsigned sB0 = __shfl_xor(B0, 32), sB1 = __shfl_xor(B1, 32);
      u32x4 w0;
      w0[0] = h ? sB0 : A0;  w0[1] = h ? sB1 : A1;
      w0[2] = h ? B0 : sA0;  w0[3] = h ? B1 : sA1;
      pa0 = __builtin_bit_cast(bf16x8, w0);   // m 0..15
    }
    {
      float p0 = __builtin_amdgcn_exp2f(s[8]  - FIXM);
      float p1 = __builtin_amdgcn_exp2f(s[9]  - FIXM);
      float p2 = __builtin_amdgcn_exp2f(s[10] - FIXM);
      float p3 = __builtin_amdgcn_exp2f(s[11] - FIXM);
      float p4 = __builtin_amdgcn_exp2f(s[12] - FIXM);
      float p5 = __builtin_amdgcn_exp2f(s[13] - FIXM);
      float p6 = __builtin_amdgcn_exp2f(s[14] - FIXM);
      float p7 = __builtin_amdgcn_exp2f(s[15] - FIXM);
      l_acc += p0 + p1 + p2 + p3 + p4 + p5 + p6 + p7;
      unsigned C0 = pack_bf16_rne(p0, p1), C1 = pack_bf16_rne(p2, p3);
      unsigned D0 = pack_bf16_rne(p4, p5), D1 = pack_bf16_rne(p6, p7);
      unsigned sC0 = __shfl_xor(C0, 32), sC1 = __shfl_xor(C1, 32);
      unsigned sD0 = __shfl_xor(D0, 32), sD1 = __shfl_xor(D1, 32);
      u32x4 w1;
      w1[0] = h ? sD0 : C0;  w1[1] = h ? sD1 : C1;
      w1[2] = h ? D0 : sC0;  w1[3] = h ? D1 : sC1;
      pa1 = __builtin_bit_cast(bf16x8, w1);   // m 16..31
    }

    // ---- O += P V : 16 mfma(32x32x16), A-frags from registers ----
    #pragma unroll
    for (int ct = 0; ct < 8; ++ct){
      int c = ct * 32 + col;
      int sw = (c >> 1) & 3;
      bf16x8 vf0 = *(const bf16x8*)&vc[c * 32 + ((h ^ sw) * 8)];
      bf16x8 vf1 = *(const bf16x8*)&vc[c * 32 + (((2 + h) ^ sw) * 8)];
      o_acc[ct] = mfma32(pa0, vf0, o_acc[ct]);
      o_acc[ct] = mfma32(pa1, vf1, o_acc[ct]);
    }

    // end-of-iter: drain DMA (vmcnt) + barrier -> next buffer valid, this
    // buffer free for the DMA issued in it+1.
    if (it < 31) __syncthreads();
  }

  // ---- epilogue: un-normalized partial (bf16) + per-row l ----
  short* op = o_part + (((size_t)(ck * 4 + b)) * 4096 + q0 + w * 32) * 256;
  #pragma unroll
  for (int r = 0; r < 16; ++r){
    int q = (r & 3) + 8 * (r >> 2) + 4 * h;
    #pragma unroll
    for (int ct = 0; ct < 8; ++ct)
      op[(size_t)q * 256 + ct * 32 + col] = f2bf(o_acc[ct][r]);
  }
  l_acc += __shfl_xor(l_acc, 32);
  if (h == 0)
    lsum[((size_t)(ck * 4 + b)) * 4096 + q0 + w * 32 + col] = l_acc;
}

// ---------------- kernel 5b: combine KV-split partials -> o_t (B,N,C) bf16 ----------------
// shared fixed M across chunks: out = (sum O_ck) / (sum l_ck)
__global__ __launch_bounds__(256) void k_comb(const short* __restrict__ o_part, const float* __restrict__ lsum,
                                              short* __restrict__ o_t)
{
  int t = blockIdx.x * 256 + threadIdx.x;
  int row = t >> 5;                          // b*4096 + n
  int c8 = (t & 31) * 8;
  float inv = 1.f / (lsum[row] + lsum[16384 + row] + lsum[2 * 16384 + row] + lsum[3 * 16384 + row]);
  size_t base = (size_t)row * 256 + c8;
  const size_t CS = (size_t)16384 * 256;
  bf16x8 a0 = *(const bf16x8*)(o_part + base);
  bf16x8 a1 = *(const bf16x8*)(o_part + CS + base);
  bf16x8 a2 = *(const bf16x8*)(o_part + 2 * CS + base);
  bf16x8 a3 = *(const bf16x8*)(o_part + 3 * CS + base);
  bf16x8 outv;
  #pragma unroll
  for (int j = 0; j < 8; ++j)
    outv[j] = f2bf((bf2f(a0[j]) + bf2f(a1[j]) + bf2f(a2[j]) + bf2f(a3[j])) * inv);
  *(bf16x8*)(o_t + base) = outv;
}

extern "C" void kernel_launch(void* const* d_in, const int* in_sizes, int n_in,
                              void* d_out, int out_size, void* d_ws, size_t ws_size,
                              hipStream_t stream)
{
  const float* x     = (const float*)d_in[0];
  const float* gw    = (const float*)d_in[1];
  const float* gb    = (const float*)d_in[2];
  const float* qkvw  = (const float*)d_in[3];
  const float* qkvb  = (const float*)d_in[4];
  const float* projw = (const float*)d_in[5];
  const float* projb = (const float*)d_in[6];
  float* out = (float*)d_out;

  char* ws = (char*)d_ws;
  float2* stats = (float2*)ws;                         // 1 KB
  short* wqb = (short*)(ws + 1024);                    // 384 KB
  short* wpb = (short*)(ws + 1024 + 393216);           // 128 KB
  short* h_t = (short*)(ws + 1024 + 393216 + 131072);  // 8 MB buffers follow
  const size_t BIG = (size_t)4 * 4096 * 256;           // elements (8 MB as bf16)
  short* q_t = h_t + BIG;
  short* k_t = q_t + BIG;
  short* v_  = k_t + BIG;
  short* o_t = v_  + BIG;
  short* o_part = o_t + BIG;                           // 4 chunks x 8 MB = 32 MB
  float* lsum = (float*)(o_part + 4 * BIG);            // 256 KB

  k_conv <<<dim3(256),  dim3(256), 0, stream>>>(qkvw, projw, wqb, wpb);
  k_stats<<<dim3(128),  dim3(256), 0, stream>>>(x, stats);
  k_norm <<<dim3(256),  dim3(256), 0, stream>>>(x, stats, gw, gb, h_t);
  k_gemm <<<dim3(768),  dim3(256), 0, stream>>>(wqb, h_t, qkvb, 6, 0, q_t, k_t, v_,
                                                (const float*)nullptr, (float*)nullptr);
  k_attn <<<dim3(512),  dim3(256), 0, stream>>>(q_t, k_t, v_, o_part, lsum);
  k_comb <<<dim3(2048), dim3(256), 0, stream>>>(o_part, lsum, o_t);
  k_gemm <<<dim3(256),  dim3(256), 0, stream>>>(wpb, o_t, projb, 2, 1,
                                                (short*)nullptr, (short*)nullptr, (short*)nullptr,
                                                x, out);
}

// Round 6
// 204.697 us; speedup vs baseline: 1.1381x; 1.1023x over previous
//
#include <hip/hip_runtime.h>
#include <cstdint>
#include <cstddef>

typedef __attribute__((ext_vector_type(8))) short bf16x8;
typedef __attribute__((ext_vector_type(4))) short s16x4;
typedef __attribute__((ext_vector_type(2))) short s16x2;
typedef __attribute__((ext_vector_type(4))) float f32x4;
typedef __attribute__((ext_vector_type(16))) float f32x16;
typedef __attribute__((ext_vector_type(4))) unsigned u32x4;

#define DEVI static __device__ __forceinline__

DEVI short f2bf(float f){
  unsigned u = __builtin_bit_cast(unsigned, f);
  u += 0x7fffu + ((u >> 16) & 1u);
  return (short)(u >> 16);
}
DEVI float bf2f(short s){
  unsigned u = ((unsigned)(unsigned short)s) << 16;
  return __builtin_bit_cast(float, u);
}
// packed RNE f32->bf16 pair (low = a, high = b). v_cvt_pk_bf16_f32 is NOT
// round-to-nearest-even (R1 post-mortem: swapping it in tripled absmax);
// software RNE matches the reference-passing numerics exactly.
DEVI unsigned pack_bf16_rne(float a, float b){
  unsigned ua = __builtin_bit_cast(unsigned, a);
  unsigned ub = __builtin_bit_cast(unsigned, b);
  ua += 0x7fffu + ((ua >> 16) & 1u);
  ub += 0x7fffu + ((ub >> 16) & 1u);
  return (ua >> 16) | (ub & 0xffff0000u);
}

DEVI f32x4 mfma16(bf16x8 a, bf16x8 b, f32x4 c){
  return __builtin_amdgcn_mfma_f32_16x16x32_bf16(a, b, c, 0, 0, 0);
}
DEVI f32x16 mfma32(bf16x8 a, bf16x8 b, f32x16 c){
  return __builtin_amdgcn_mfma_f32_32x32x16_bf16(a, b, c, 0, 0, 0);
}

// q pre-scale: C^-0.5 * log2(e) so attention runs in exp2 domain
#define QSC 0.09016844005555897f
// fixed softmax "max" (exp2 domain): exact math (normalization cancels it);
// scores bounded ~N(0,1.44) so p=exp2(s-8) can neither overflow nor denormal.
#define FIXM 8.0f

// ---------------- kernel 2: groupnorm stats (+ fused weight fp32->bf16 conv) ----------------
// blocks 0..127: stats; blocks 128..383: weight conversion (saves a dispatch).
__global__ __launch_bounds__(256) void k_stats(const float* __restrict__ x, float2* __restrict__ st,
                                               const float* __restrict__ wq, const float* __restrict__ wp,
                                               short* __restrict__ wqb, short* __restrict__ wpb){
  if (blockIdx.x >= 128){
    int t = (blockIdx.x - 128) * 256 + threadIdx.x;
    for (int i = t; i < 768 * 256; i += 256 * 256) wqb[i] = f2bf(wq[i]);
    if (t < 256 * 256) wpb[t] = f2bf(wp[t]);
    return;
  }
  int b = blockIdx.x >> 5, g = blockIdx.x & 31;
  const f32x4* p = (const f32x4*)(x + ((size_t)(b * 256 + g * 8)) * 4096);
  float s = 0.f, ss = 0.f;
  for (int i = threadIdx.x; i < 8192; i += 256){
    f32x4 v = p[i];
    s  += v[0] + v[1] + v[2] + v[3];
    ss += v[0]*v[0] + v[1]*v[1] + v[2]*v[2] + v[3]*v[3];
  }
  for (int d = 32; d; d >>= 1){ s += __shfl_down(s, d); ss += __shfl_down(ss, d); }
  __shared__ float a0[4], a1[4];
  int w = threadIdx.x >> 6;
  if ((threadIdx.x & 63) == 0){ a0[w] = s; a1[w] = ss; }
  __syncthreads();
  if (threadIdx.x == 0){
    s = a0[0] + a0[1] + a0[2] + a0[3];
    ss = a1[0] + a1[1] + a1[2] + a1[3];
    float mean = s * (1.f / 32768.f);
    float var = ss * (1.f / 32768.f) - mean * mean;
    st[blockIdx.x] = make_float2(mean, rsqrtf(var + 1e-5f));
  }
}

// ---------------- kernel 3: normalize + transpose -> h_t (B,N,C) bf16 ----------------
__global__ __launch_bounds__(256) void k_norm(const float* __restrict__ x, const float2* __restrict__ st,
                                              const float* __restrict__ gw, const float* __restrict__ gb,
                                              short* __restrict__ h_t){
  __shared__ short t[256][66];
  int b = blockIdx.x >> 6;
  int n0 = (blockIdx.x & 63) * 64;
  int tid = threadIdx.x;
  for (int r = 0; r < 16; ++r){
    int idx = tid + r * 256;
    int c = idx >> 4, ch = idx & 15;
    f32x4 v = *(const f32x4*)(x + ((size_t)(b * 256 + c)) * 4096 + n0 + ch * 4);
    float2 s = st[b * 32 + (c >> 3)];
    float wv = gw[c] * s.y;
    float bv = gb[c] - s.x * wv;
    s16x2 p0, p1;
    p0[0] = f2bf(v[0] * wv + bv); p0[1] = f2bf(v[1] * wv + bv);
    p1[0] = f2bf(v[2] * wv + bv); p1[1] = f2bf(v[3] * wv + bv);
    *(s16x2*)&t[c][ch * 4]     = p0;
    *(s16x2*)&t[c][ch * 4 + 2] = p1;
  }
  __syncthreads();
  for (int r = 0; r < 8; ++r){
    int idx = tid + r * 256;
    int n = idx >> 5, cc = idx & 31;
    bf16x8 pk;
    #pragma unroll
    for (int j = 0; j < 8; ++j) pk[j] = t[cc * 8 + j][n];
    *(bf16x8*)(h_t + ((size_t)(b * 4096 + n0 + n)) * 256 + cc * 8) = pk;
  }
}

// ---------------- kernel 4/6: 128x128-tile bf16 MFMA GEMM ----------------
__global__ __launch_bounds__(256) void k_gemm(const short* __restrict__ A,
                                              const short* __restrict__ Bsrc,
                                              const float* __restrict__ bias,
                                              int mtiles, int mode,
                                              short* __restrict__ q_t, short* __restrict__ k_t,
                                              short* __restrict__ v_,
                                              const float* __restrict__ xres, float* __restrict__ outp)
{
  __shared__ short a_s[128 * 72];
  __shared__ short b_s[128 * 72];
  int t = blockIdx.x;
  int mt = t % mtiles; t /= mtiles;
  int nt = t & 31; int b = t >> 5;
  int o0 = mt * 128, n0 = nt * 128;
  int tid = threadIdx.x;
  int lane = tid & 63, w = tid >> 6;
  int col = lane & 15, quad = lane >> 4;
  int wo = (w >> 1) * 64, wn = (w & 1) * 64;

  f32x4 acc[4][4];
  #pragma unroll
  for (int i = 0; i < 4; ++i)
    #pragma unroll
    for (int j = 0; j < 4; ++j)
      #pragma unroll
      for (int r = 0; r < 4; ++r) acc[i][j][r] = 0.f;

  for (int kk = 0; kk < 4; ++kk){
    int k0 = kk * 64;
    #pragma unroll
    for (int r = 0; r < 4; ++r){
      int idx = tid + r * 256;
      int row = idx >> 3, ch = idx & 7;
      *(bf16x8*)&a_s[row * 72 + ch * 8] = *(const bf16x8*)(A + (size_t)(o0 + row) * 256 + k0 + ch * 8);
      *(bf16x8*)&b_s[row * 72 + ch * 8] = *(const bf16x8*)(Bsrc + ((size_t)(b * 4096 + n0 + row)) * 256 + k0 + ch * 8);
    }
    __syncthreads();
    #pragma unroll
    for (int kc = 0; kc < 2; ++kc){
      bf16x8 af[4], bfr[4];
      #pragma unroll
      for (int i = 0; i < 4; ++i) af[i]  = *(bf16x8*)&a_s[(wo + i * 16 + col) * 72 + kc * 32 + quad * 8];
      #pragma unroll
      for (int j = 0; j < 4; ++j) bfr[j] = *(bf16x8*)&b_s[(wn + j * 16 + col) * 72 + kc * 32 + quad * 8];
      #pragma unroll
      for (int i = 0; i < 4; ++i)
        #pragma unroll
        for (int j = 0; j < 4; ++j)
          acc[i][j] = mfma16(af[i], bfr[j], acc[i][j]);
    }
    __syncthreads();
  }

  float bv[4][4];
  #pragma unroll
  for (int i = 0; i < 4; ++i)
    #pragma unroll
    for (int r = 0; r < 4; ++r) bv[i][r] = bias[o0 + wo + i * 16 + quad * 4 + r];

  if (mode == 0){
    int region = o0 >> 8;              // 0=q 1=k 2=v (block-uniform)
    int obase = (o0 & 255) + wo;
    if (region < 2){
      short* dst = region ? k_t : q_t;
      float sc = region ? 1.0f : QSC;
      #pragma unroll
      for (int i = 0; i < 4; ++i)
        #pragma unroll
        for (int j = 0; j < 4; ++j){
          int n = n0 + wn + j * 16 + col;
          s16x4 pk;
          #pragma unroll
          for (int r = 0; r < 4; ++r) pk[r] = f2bf((acc[i][j][r] + bv[i][r]) * sc);
          *(s16x4*)(dst + ((size_t)(b * 4096 + n)) * 256 + obase + i * 16 + quad * 4) = pk;
        }
    } else {
      #pragma unroll
      for (int i = 0; i < 4; ++i)
        #pragma unroll
        for (int r = 0; r < 4; ++r){
          int oo = obase + i * 16 + quad * 4 + r;
          #pragma unroll
          for (int j = 0; j < 4; ++j){
            int n = n0 + wn + j * 16 + col;
            v_[((size_t)(b * 256 + oo)) * 4096 + n] = f2bf(acc[i][j][r] + bv[i][r]);
          }
        }
    }
  } else {
    #pragma unroll
    for (int i = 0; i < 4; ++i)
      #pragma unroll
      for (int r = 0; r < 4; ++r){
        int oo = o0 + wo + i * 16 + quad * 4 + r;
        #pragma unroll
        for (int j = 0; j < 4; ++j){
          int n = n0 + wn + j * 16 + col;
          size_t off = ((size_t)(b * 256 + oo)) * 4096 + n;
          outp[off] = xres[off] + acc[i][j][r] + bv[i][r];
        }
      }
  }
}

// ---------------- kernel 5: flash attention (fixed-max softmax, in-reg P) ----------------
// grid = 512: (chunk=idx&15, qt=idx>>4); block = 4 waves x 32 q-rows = 128 q; BM=32.
// R3 anchor structure: SINGLE-buffer reg-staged LDS (R2/R4/R5 post-mortems:
// both reg-dbuf (+32 VGPR) and global_load_lds-dbuf re-added ~10 MB parasitic
// HBM traffic and lost 20-28 us; this kernel lives at the 256-reg cliff).
// R6 delta: K swizzle widened 3->5 bits (chunk ^ (row&31)): QK^T A-frag read
// has lane=m reading chunk (ks2*2+h)^(m&31) -> 32 distinct 16B slots over the
// 32 read lanes (was 8 slots / 4-way aliasing with &7). Write side stays free
// (2 rows/wave-instr, bijective within row). Register-neutral.
// QK^T computed transposed (S^T = mfma32(K, Q)) so each lane owns P for
// q = lane&31: softmax + RNE bf16 pack + h-half exchange fully in registers.
__global__ __launch_bounds__(256, 2) void k_attn(const short* __restrict__ q_t, const short* __restrict__ k_t,
                                                 const short* __restrict__ v_,
                                                 short* __restrict__ o_part, float* __restrict__ lsum)
{
  __shared__ short k_s[32 * 256];      // [m][c], 16B chunk p stored at p^(m&31)
  __shared__ short v_s[256 * 32];      // [c][m], 16B chunk p stored at p^((c>>1)&3)
  int idx = blockIdx.x;
  int qt = idx >> 4;
  int chunk = idx & 15;
  int b  = chunk >> 2;
  int ck = chunk & 3;
  int q0 = qt * 128;
  int tid = threadIdx.x, lane = tid & 63, w = tid >> 6;
  int col = lane & 31, h = lane >> 5;

  // Q fragments: 32 q/wave, full K=256 resident (16 frags = 64 VGPR).
  const short* qp = q_t + ((size_t)(b * 4096 + q0 + w * 32 + col)) * 256 + h * 8;
  bf16x8 qf[16];
  #pragma unroll
  for (int ks2 = 0; ks2 < 16; ++ks2) qf[ks2] = *(const bf16x8*)(qp + ks2 * 16);

  const short* kcb = k_t + ((size_t)(b * 4096 + ck * 1024)) * 256;
  const short* vcb = v_  + ((size_t)b) * 256 * 4096 + ck * 1024;

  // staging lane mapping
  int k_r = w * 8 + (lane >> 5);     // +i*2 : K row within tile
  int k_p = lane & 31;               // K 16B-chunk position
  int v_c = w * 64 + (lane >> 2);    // +i*16 : V c-row
  int v_p = lane & 3;                // V 16B-chunk position

  f32x16 o_acc[8];
  #pragma unroll
  for (int ct = 0; ct < 8; ++ct)
    #pragma unroll
    for (int r = 0; r < 16; ++r) o_acc[ct][r] = 0.f;
  float l_acc = 0.f;

  #pragma unroll 1
  for (int it = 0; it < 32; ++it){
    int m0 = it * 32;
    // ---- stage tile it (transient regs; loads issued before barrier so their
    //      latency overlaps the barrier wait) ----
    bf16x8 kst[4], vst[4];
    #pragma unroll
    for (int i = 0; i < 4; ++i){
      kst[i] = *(const bf16x8*)(kcb + (size_t)(m0 + k_r + i * 2) * 256 + k_p * 8);
      vst[i] = *(const bf16x8*)(vcb + (size_t)(v_c + i * 16) * 4096 + m0 + v_p * 8);
    }
    if (it) __syncthreads();           // all waves done reading prev tile
    #pragma unroll
    for (int i = 0; i < 4; ++i){
      int r = k_r + i * 2;
      *(bf16x8*)&k_s[r * 256 + (k_p ^ (r & 31)) * 8] = kst[i];
      int c = v_c + i * 16;
      *(bf16x8*)&v_s[c * 32 + (v_p ^ ((c >> 1) & 3)) * 8] = vst[i];
    }
    __syncthreads();                   // tile visible

    // ---- S^T = K Q^T : 16 mfma(32x32x16); C: col = q (lane&31), row = m ----
    f32x16 s;
    #pragma unroll
    for (int r = 0; r < 16; ++r) s[r] = 0.f;
    #pragma unroll
    for (int ks2 = 0; ks2 < 16; ++ks2){
      bf16x8 kb = *(const bf16x8*)&k_s[col * 256 + (((ks2 * 2 + h) ^ (col & 31)) * 8)];
      s = mfma32(kb, qf[ks2], s);
    }

    // ---- fixed-max softmax, fully in registers, two halves ----
    // lane holds p[q = lane&31][m = (r&3) + 8*(r>>2) + 4*h]
    bf16x8 pa0, pa1;
    {
      float p0 = __builtin_amdgcn_exp2f(s[0] - FIXM);
      float p1 = __builtin_amdgcn_exp2f(s[1] - FIXM);
      float p2 = __builtin_amdgcn_exp2f(s[2] - FIXM);
      float p3 = __builtin_amdgcn_exp2f(s[3] - FIXM);
      float p4 = __builtin_amdgcn_exp2f(s[4] - FIXM);
      float p5 = __builtin_amdgcn_exp2f(s[5] - FIXM);
      float p6 = __builtin_amdgcn_exp2f(s[6] - FIXM);
      float p7 = __builtin_amdgcn_exp2f(s[7] - FIXM);
      l_acc += p0 + p1 + p2 + p3 + p4 + p5 + p6 + p7;
      unsigned A0 = pack_bf16_rne(p0, p1), A1 = pack_bf16_rne(p2, p3);
      unsigned B0 = pack_bf16_rne(p4, p5), B1 = pack_bf16_rne(p6, p7);
      unsigned sA0 = __shfl_xor(A0, 32), sA1 = __shfl_xor(A1, 32);
      unsigned sB0 = __shfl_xor(B0, 32), sB1 = __shfl_xor(B1, 32);
      u32x4 w0;
      w0[0] = h ? sB0 : A0;  w0[1] = h ? sB1 : A1;
      w0[2] = h ? B0 : sA0;  w0[3] = h ? B1 : sA1;
      pa0 = __builtin_bit_cast(bf16x8, w0);   // m 0..15
    }
    {
      float p0 = __builtin_amdgcn_exp2f(s[8]  - FIXM);
      float p1 = __builtin_amdgcn_exp2f(s[9]  - FIXM);
      float p2 = __builtin_amdgcn_exp2f(s[10] - FIXM);
      float p3 = __builtin_amdgcn_exp2f(s[11] - FIXM);
      float p4 = __builtin_amdgcn_exp2f(s[12] - FIXM);
      float p5 = __builtin_amdgcn_exp2f(s[13] - FIXM);
      float p6 = __builtin_amdgcn_exp2f(s[14] - FIXM);
      float p7 = __builtin_amdgcn_exp2f(s[15] - FIXM);
      l_acc += p0 + p1 + p2 + p3 + p4 + p5 + p6 + p7;
      unsigned C0 = pack_bf16_rne(p0, p1), C1 = pack_bf16_rne(p2, p3);
      unsigned D0 = pack_bf16_rne(p4, p5), D1 = pack_bf16_rne(p6, p7);
      unsigned sC0 = __shfl_xor(C0, 32), sC1 = __shfl_xor(C1, 32);
      unsigned sD0 = __shfl_xor(D0, 32), sD1 = __shfl_xor(D1, 32);
      u32x4 w1;
      w1[0] = h ? sD0 : C0;  w1[1] = h ? sD1 : C1;
      w1[2] = h ? D0 : sC0;  w1[3] = h ? D1 : sC1;
      pa1 = __builtin_bit_cast(bf16x8, w1);   // m 16..31
    }

    // ---- O += P V : 16 mfma(32x32x16), A-frags from registers ----
    #pragma unroll
    for (int ct = 0; ct < 8; ++ct){
      int c = ct * 32 + col;
      int sw = (c >> 1) & 3;
      bf16x8 vf0 = *(const bf16x8*)&v_s[c * 32 + ((h ^ sw) * 8)];
      bf16x8 vf1 = *(const bf16x8*)&v_s[c * 32 + (((2 + h) ^ sw) * 8)];
      o_acc[ct] = mfma32(pa0, vf0, o_acc[ct]);
      o_acc[ct] = mfma32(pa1, vf1, o_acc[ct]);
    }
  }

  // ---- epilogue: un-normalized partial (bf16) + per-row l ----
  short* op = o_part + (((size_t)(ck * 4 + b)) * 4096 + q0 + w * 32) * 256;
  #pragma unroll
  for (int r = 0; r < 16; ++r){
    int q = (r & 3) + 8 * (r >> 2) + 4 * h;
    #pragma unroll
    for (int ct = 0; ct < 8; ++ct)
      op[(size_t)q * 256 + ct * 32 + col] = f2bf(o_acc[ct][r]);
  }
  l_acc += __shfl_xor(l_acc, 32);
  if (h == 0)
    lsum[((size_t)(ck * 4 + b)) * 4096 + q0 + w * 32 + col] = l_acc;
}

// ---------------- kernel 5b: combine KV-split partials -> o_t (B,N,C) bf16 ----------------
// shared fixed M across chunks: out = (sum O_ck) / (sum l_ck)
__global__ __launch_bounds__(256) void k_comb(const short* __restrict__ o_part, const float* __restrict__ lsum,
                                              short* __restrict__ o_t)
{
  int t = blockIdx.x * 256 + threadIdx.x;
  int row = t >> 5;                          // b*4096 + n
  int c8 = (t & 31) * 8;
  float inv = 1.f / (lsum[row] + lsum[16384 + row] + lsum[2 * 16384 + row] + lsum[3 * 16384 + row]);
  size_t base = (size_t)row * 256 + c8;
  const size_t CS = (size_t)16384 * 256;
  bf16x8 a0 = *(const bf16x8*)(o_part + base);
  bf16x8 a1 = *(const bf16x8*)(o_part + CS + base);
  bf16x8 a2 = *(const bf16x8*)(o_part + 2 * CS + base);
  bf16x8 a3 = *(const bf16x8*)(o_part + 3 * CS + base);
  bf16x8 outv;
  #pragma unroll
  for (int j = 0; j < 8; ++j)
    outv[j] = f2bf((bf2f(a0[j]) + bf2f(a1[j]) + bf2f(a2[j]) + bf2f(a3[j])) * inv);
  *(bf16x8*)(o_t + base) = outv;
}

extern "C" void kernel_launch(void* const* d_in, const int* in_sizes, int n_in,
                              void* d_out, int out_size, void* d_ws, size_t ws_size,
                              hipStream_t stream)
{
  const float* x     = (const float*)d_in[0];
  const float* gw    = (const float*)d_in[1];
  const float* gb    = (const float*)d_in[2];
  const float* qkvw  = (const float*)d_in[3];
  const float* qkvb  = (const float*)d_in[4];
  const float* projw = (const float*)d_in[5];
  const float* projb = (const float*)d_in[6];
  float* out = (float*)d_out;

  char* ws = (char*)d_ws;
  float2* stats = (float2*)ws;                         // 1 KB
  short* wqb = (short*)(ws + 1024);                    // 384 KB
  short* wpb = (short*)(ws + 1024 + 393216);           // 128 KB
  short* h_t = (short*)(ws + 1024 + 393216 + 131072);  // 8 MB buffers follow
  const size_t BIG = (size_t)4 * 4096 * 256;           // elements (8 MB as bf16)
  short* q_t = h_t + BIG;
  short* k_t = q_t + BIG;
  short* v_  = k_t + BIG;
  short* o_t = v_  + BIG;
  short* o_part = o_t + BIG;                           // 4 chunks x 8 MB = 32 MB
  float* lsum = (float*)(o_part + 4 * BIG);            // 256 KB

  k_stats<<<dim3(384),  dim3(256), 0, stream>>>(x, stats, qkvw, projw, wqb, wpb);
  k_norm <<<dim3(256),  dim3(256), 0, stream>>>(x, stats, gw, gb, h_t);
  k_gemm <<<dim3(768),  dim3(256), 0, stream>>>(wqb, h_t, qkvb, 6, 0, q_t, k_t, v_,
                                                (const float*)nullptr, (float*)nullptr);
  k_attn <<<dim3(512),  dim3(256), 0, stream>>>(q_t, k_t, v_, o_part, lsum);
  k_comb <<<dim3(2048), dim3(256), 0, stream>>>(o_part, lsum, o_t);
  k_gemm <<<dim3(256),  dim3(256), 0, stream>>>(wpb, o_t, projb, 2, 1,
                                                (short*)nullptr, (short*)nullptr, (short*)nullptr,
                                                x, out);
}